// Round 10
// baseline (2182.810 us; speedup 1.0000x reference)
//
#include <hip/hip_runtime.h>
#include <hip/hip_bf16.h>
#include <cstdint>

#define NNODES 50000
#define MPAD   50048   // 782 * 64
#define NROWT  782     // MPAD/64
#define NEDGES 800000
#define DIN 128
#define HID 256
#define NCLS 40
#define NBLK 3
#define EPSV 1e-5f

typedef __bf16 bf16x8 __attribute__((ext_vector_type(8)));
typedef float  f32x4  __attribute__((ext_vector_type(4)));
typedef unsigned short us4v __attribute__((ext_vector_type(4)));
typedef unsigned short us8v __attribute__((ext_vector_type(8)));

// round-to-nearest-even fp32 -> bf16 bits
__device__ __forceinline__ unsigned short bf_rtn(float x) {
  unsigned u = __float_as_uint(x);
  return (unsigned short)((u + 0x7fffu + ((u >> 16) & 1u)) >> 16);
}
__device__ __forceinline__ float bf_f(unsigned short h) {
  return __uint_as_float((unsigned)h << 16);
}
// 3-plane split: x ~= h + m + l (each bf16)
__device__ __forceinline__ void split4(float4 a, us4v& h, us4v& m, us4v& l) {
  float v[4] = {a.x, a.y, a.z, a.w};
#pragma unroll
  for (int i = 0; i < 4; i++) {
    unsigned short hh = bf_rtn(v[i]);
    float r1 = v[i] - bf_f(hh);
    unsigned short mm = bf_rtn(r1);
    float r2 = r1 - bf_f(mm);
    h[i] = hh; m[i] = mm; l[i] = bf_rtn(r2);
  }
}

// Plane image of a 64x32 A-tile (12288 B): [plane 3][k8 0..3][row 0..63][16B].
// Global activation-plane buffer: [rowtile][ktile] x 12288 B, KT tiles per row.
__device__ __forceinline__ void plane_store(char* base, int KT, int r, int c, float v) {
  size_t o = ((size_t)((r >> 6) * KT + (c >> 5))) * 12288
           + (size_t)(((c >> 3) & 3) * 1024 + (r & 63) * 16 + (c & 7) * 2);
  unsigned short h = bf_rtn(v);
  float r1 = v - bf_f(h);
  unsigned short m = bf_rtn(r1);
  unsigned short l = bf_rtn(r1 - bf_f(m));
  *(unsigned short*)(base + o)        = h;
  *(unsigned short*)(base + o + 4096) = m;
  *(unsigned short*)(base + o + 8192) = l;
}

// async global->LDS, 16B per lane. gsrc is PER-LANE; ldst wave-uniform (HW adds lane*16).
__device__ __forceinline__ void glds16(const void* gsrc, void* ldst) {
  __builtin_amdgcn_global_load_lds((const __attribute__((address_space(1))) void*)gsrc,
                                   (__attribute__((address_space(3))) void*)ldst,
                                   16, 0, 0);
}

// ---------------- CSR build ----------------
__global__ void hist_kernel(const int* __restrict__ dst, int* __restrict__ cnt, int E) {
  int e = blockIdx.x * blockDim.x + threadIdx.x;
  if (e < E) atomicAdd(&cnt[dst[e]], 1);
}

__global__ void scan_kernel(const int* __restrict__ cnt, int* __restrict__ row_ptr,
                            float* __restrict__ inv_cnt, int N) {
  __shared__ int sums[1024];
  int t = threadIdx.x;
  int chunk = (N + 1023) >> 10;
  int beg = t * chunk;
  int end = beg + chunk; if (end > N) end = N;
  int s = 0;
  for (int i = beg; i < end; ++i) s += cnt[i];
  sums[t] = s;
  __syncthreads();
  for (int off = 1; off < 1024; off <<= 1) {
    int v = 0;
    if (t >= off) v = sums[t - off];
    __syncthreads();
    sums[t] += v;
    __syncthreads();
  }
  int run = (t == 0) ? 0 : sums[t - 1];
  for (int i = beg; i < end; ++i) {
    row_ptr[i] = run;
    int c = cnt[i];
    inv_cnt[i] = 1.0f / (float)(c > 0 ? c : 1);
    run += c;
  }
  if (t == 1023) row_ptr[N] = run;
}

__global__ void fill_kernel(const int* __restrict__ src, const int* __restrict__ dst,
                            const int* __restrict__ row_ptr, int* __restrict__ fillc,
                            int* __restrict__ col, int E) {
  int e = blockIdx.x * blockDim.x + threadIdx.x;
  if (e < E) {
    int d = dst[e];
    int pos = atomicAdd(&fillc[d], 1);
    col[row_ptr[d] + pos] = src[e];
  }
}

// ---------------- mean aggregation: fp32 out (small) or planes out (big) ------
__global__ __launch_bounds__(256)
void agg_kernel(const float* __restrict__ x, float* __restrict__ outf,
                char* __restrict__ outp,
                const int* __restrict__ row_ptr, const int* __restrict__ col,
                const float* __restrict__ inv_cnt) {
  int n = blockIdx.x;
  int h = threadIdx.x;
  int beg = row_ptr[n], end = row_ptr[n + 1];
  float s = 0.0f;
  for (int j = beg; j < end; ++j) {
    int c = col[j];
    s += x[(long)c * HID + h];
  }
  float v = s * inv_cnt[n];
  if (outp) plane_store(outp, 8, n, h, v);
  else      outf[(long)n * HID + h] = v;
}

// ---------------- fold BN params ----------------
__global__ void fold_kernel(const float* __restrict__ b1l, const float* __restrict__ g1,
                            const float* __restrict__ bb1, const float* __restrict__ m1,
                            const float* __restrict__ v1,
                            const float* __restrict__ b2l, const float* __restrict__ g2,
                            const float* __restrict__ bb2, const float* __restrict__ m2,
                            const float* __restrict__ v2,
                            float* __restrict__ S1, float* __restrict__ T1,
                            float* __restrict__ S2, float* __restrict__ T2) {
  int idx = blockIdx.x * 256 + threadIdx.x;  // 0..767
  float s1 = g1[idx] * rsqrtf(v1[idx] + EPSV);
  S1[idx] = s1;
  T1[idx] = (b1l[idx] - m1[idx]) * s1 + bb1[idx];
  float s2 = g2[idx] * rsqrtf(v2[idx] + EPSV);
  S2[idx] = s2;
  T2[idx] = (b2l[idx] - m2[idx]) * s2 + bb2[idx];
}

// ---------------- weight prep (layout unchanged from r6-r8) ----------------
#define PREP_TOTAL 368640
struct PrepDescs {
  const float* src[16];
  unsigned dst_off[16];
  int N[16];
  int cum[16];
};
__global__ __launch_bounds__(256)
void prep_kernel(PrepDescs pd, char* out) {
  int i = blockIdx.x * 256 + threadIdx.x;
  if (i >= PREP_TOTAL) return;
  int j = 0;
  while (i >= pd.cum[j]) j++;
  int li = i - (j ? pd.cum[j - 1] : 0);
  int c = li % 12;
  int t = li / 12;
  int N = pd.N[j];
  int n = t % N;
  int kt = t / N;
  const float* src = pd.src[j];
  char* base = out + pd.dst_off[j] + (size_t)kt * N * 192;
  int p, k8;
  size_t addr;
  if (c < 8) {
    int d = c ^ (n & 7);
    p = d >> 2; k8 = d & 3;
    addr = (size_t)n * 128 + (size_t)c * 16;
  } else {
    p = 2; k8 = c - 8;
    addr = (size_t)N * 128 + ((size_t)k8 * N + n) * 16;
  }
  us8v v;
#pragma unroll
  for (int xj = 0; xj < 8; xj++) {
    float w = src[(size_t)(kt * 32 + k8 * 8 + xj) * N + n];
    unsigned short h = bf_rtn(w);
    if (p == 0) { v[xj] = h; continue; }
    float r1 = w - bf_f(h);
    unsigned short m = bf_rtn(r1);
    v[xj] = (p == 1) ? m : bf_rtn(r1 - bf_f(m));
  }
  *reinterpret_cast<us8v*>(base + addr) = v;
}

// ---------------- fused 3-plane split-bf16 MFMA GEMM ----------------
// 64x128 tile, 4 waves (2x2), double-buffered, prefetch-pipelined, 2 blocks/CU.
// Per phase the A operand is either a pre-split plane buffer (glds, no VALU) or
// fp32 (in-kernel split). Both write the SAME plane-image LDS layout, so one
// fragment-read path serves both. Product order h·h,h·m,m·h,m·m,h·l,l·h and
// k-order FIXED (absmax determinism — identical to r8).
template<bool GATED>
__global__ __launch_bounds__(256)
void gemm_mfma(const char* __restrict__ A1p, const float* __restrict__ A1f,
               const char* __restrict__ B1, int K1,
               const float* __restrict__ A2f, const char* __restrict__ B2, int K2,
               const float* __restrict__ AGf, const char* __restrict__ BG,
               const float* __restrict__ Gb,
               const float* __restrict__ Sc, const float* __restrict__ Tc,
               const float* __restrict__ resid, float* __restrict__ C,
               int Bn, int Mguard, int do_relu) {
  __shared__ __align__(16) char A_lds[2][12288];
  __shared__ __align__(16) char B_lds[2][24576];
  const int tid  = threadIdx.x;
  const int wv   = tid >> 6;
  const int lane = tid & 63;
  const int l15  = lane & 15;
  const int quad = lane >> 4;
  const int NC   = Bn >> 7;
  const int n0   = (blockIdx.x % NC) * 128;
  const int m0   = (blockIdx.x / NC) * 64;
  const int rt   = m0 >> 6;
  const int wm   = wv >> 1;
  const int wn   = wv & 1;
  const int sr   = tid >> 3;        // staging row 0..31 (+32)
  const int c0   = (tid & 7) * 4;   // staging col (fp32 within 32)
  const int aoff = ((c0 >> 3) & 3) * 1024 + (c0 & 7) * 2;  // k8*1024 + byte-off

  f32x4 acc1[2][4];
#pragma unroll
  for (int i = 0; i < 2; i++)
#pragma unroll
    for (int j = 0; j < 4; j++) acc1[i][j] = (f32x4){0.f, 0.f, 0.f, 0.f};
  f32x4 acc2[GATED ? 2 : 1][GATED ? 4 : 1];
  if constexpr (GATED) {
#pragma unroll
    for (int i = 0; i < 2; i++)
#pragma unroll
      for (int j = 0; j < 4; j++) acc2[i][j] = (f32x4){0.f, 0.f, 0.f, 0.f};
  }

  int buf = 0;

  auto issueApl = [&](const char* Ap, int KT, int kt, int b) {
    const char* src = Ap + ((size_t)(rt * KT + kt)) * 12288 + wv * 3072 + (size_t)lane * 16;
    char* dst = &A_lds[b][wv * 3072];
#pragma unroll
    for (int j = 0; j < 3; ++j)
      glds16(src + j * 1024, dst + j * 1024);
  };
  // B image per 128-col block-tile: [hm: 128 rows x 128B][lo: 4 k8 x 128 rows x 16B]
  auto issueB = [&](const char* Bp, int kt, int b) {
    const char* tb = Bp + (size_t)kt * ((size_t)Bn * 192);
#pragma unroll
    for (int j = 0; j < 6; ++j) {
      int o = wv * 6144 + j * 1024;
      const char* src;
      if (o < 16384) {
        src = tb + (size_t)n0 * 128 + o;
      } else {
        int ol = o - 16384;
        int k8 = ol >> 11;
        int within = ol & 2047;
        src = tb + (size_t)Bn * 128 + (size_t)k8 * Bn * 16 + (size_t)n0 * 16 + within;
      }
      glds16(src + (size_t)lane * 16, &B_lds[b][o]);
    }
  };
  auto storeA = [&](float4 (&a)[2], int b) {
#pragma unroll
    for (int i = 0; i < 2; i++) {
      us4v h4, m4, l4;
      split4(a[i], h4, m4, l4);
      char* p0 = &A_lds[b][(size_t)(sr + i * 32) * 16 + aoff];
      *reinterpret_cast<us4v*>(p0)        = h4;
      *reinterpret_cast<us4v*>(p0 + 4096) = m4;
      *reinterpret_cast<us4v*>(p0 + 8192) = l4;
    }
  };

  auto phase = [&](const char* Apl, const float* Af, const char* Bp,
                   int K, f32x4 (&acc)[2][4]) {
    const int KT = K / 32;
    const bool pl = (Apl != nullptr);
    bool g[2];
    const float* ap[2];
    if (!pl) {
#pragma unroll
      for (int i = 0; i < 2; i++) {
        int row = m0 + sr + i * 32;
        g[i] = row < Mguard;
        ap[i] = Af + (size_t)row * K + c0;
      }
    }
    // prologue: tile 0 into current buf (WAR-safe vs previous phase per barrier analysis)
    issueB(Bp, 0, buf);
    if (pl) {
      issueApl(Apl, KT, 0, buf);
    } else {
      float4 a[2];
#pragma unroll
      for (int i = 0; i < 2; i++)
        a[i] = g[i] ? *reinterpret_cast<const float4*>(ap[i]) : make_float4(0.f, 0.f, 0.f, 0.f);
      storeA(a, buf);
    }
    for (int kt = 0; kt < KT; ++kt) {
      __syncthreads();  // drains glds (kt); publishes A/B LDS images
      // 1) LDS -> fragment registers
      bf16x8 ah[2], am[2], al[2];
#pragma unroll
      for (int mt = 0; mt < 2; mt++) {
        const char* ra = &A_lds[buf][quad * 1024 + (size_t)(wm * 32 + mt * 16 + l15) * 16];
        ah[mt] = *reinterpret_cast<const bf16x8*>(ra);
        am[mt] = *reinterpret_cast<const bf16x8*>(ra + 4096);
        al[mt] = *reinterpret_cast<const bf16x8*>(ra + 8192);
      }
      bf16x8 bh[4], bm_[4], bl[4];
#pragma unroll
      for (int nt = 0; nt < 4; nt++) {
        int ln = wn * 64 + nt * 16 + l15;
        int sw = ln & 7;
        const char* rb = &B_lds[buf][(size_t)ln * 128];
        bh[nt]  = *reinterpret_cast<const bf16x8*>(rb + ((quad ^ sw) * 16));
        bm_[nt] = *reinterpret_cast<const bf16x8*>(rb + (((4 + quad) ^ sw) * 16));
        bl[nt]  = *reinterpret_cast<const bf16x8*>(
            &B_lds[buf][16384 + ((size_t)quad * 128 + ln) * 16]);
      }
      // 2) issue next tile's loads (in flight across the MFMA burst)
      const bool pf = (kt + 1 < KT);
      float4 a[2];
      if (pf) {
        issueB(Bp, kt + 1, buf ^ 1);
        if (pl) {
          issueApl(Apl, KT, kt + 1, buf ^ 1);
        } else {
#pragma unroll
          for (int i = 0; i < 2; i++)
            a[i] = g[i] ? *reinterpret_cast<const float4*>(ap[i] + (kt + 1) * 32)
                        : make_float4(0.f, 0.f, 0.f, 0.f);
        }
      }
      // 3) MFMA burst (order fixed: nt, mt, 6 products)
#pragma unroll
      for (int nt = 0; nt < 4; nt++) {
#pragma unroll
        for (int mt = 0; mt < 2; mt++) {
          acc[mt][nt] = __builtin_amdgcn_mfma_f32_16x16x32_bf16(ah[mt], bh[nt],  acc[mt][nt], 0, 0, 0);
          acc[mt][nt] = __builtin_amdgcn_mfma_f32_16x16x32_bf16(ah[mt], bm_[nt], acc[mt][nt], 0, 0, 0);
          acc[mt][nt] = __builtin_amdgcn_mfma_f32_16x16x32_bf16(am[mt], bh[nt],  acc[mt][nt], 0, 0, 0);
          acc[mt][nt] = __builtin_amdgcn_mfma_f32_16x16x32_bf16(am[mt], bm_[nt], acc[mt][nt], 0, 0, 0);
          acc[mt][nt] = __builtin_amdgcn_mfma_f32_16x16x32_bf16(ah[mt], bl[nt],  acc[mt][nt], 0, 0, 0);
          acc[mt][nt] = __builtin_amdgcn_mfma_f32_16x16x32_bf16(al[mt], bh[nt],  acc[mt][nt], 0, 0, 0);
        }
      }
      // 4) stage next A tile (fp32 path)
      if (pf && !pl) storeA(a, buf ^ 1);
      buf ^= 1;
    }
  };

  phase(A1p, A1f, B1, K1, acc1);
  if (A2f) phase(nullptr, A2f, B2, K2, acc1);
  if constexpr (GATED) phase(nullptr, AGf, BG, HID, acc2);

  // epilogue. C/D layout: col = lane&15, row = quad*4 + reg  [m89-verified]
#pragma unroll
  for (int nt = 0; nt < 4; nt++) {
    int colc = n0 + wn * 64 + nt * 16 + l15;
    float sc = Sc ? Sc[colc] : 1.0f;
    float tc = Tc[colc];
    float gb = 0.0f;
    if constexpr (GATED) gb = Gb[colc];
#pragma unroll
    for (int mt = 0; mt < 2; mt++) {
#pragma unroll
      for (int r = 0; r < 4; r++) {
        int row = m0 + wm * 32 + mt * 16 + quad * 4 + r;
        size_t base = (size_t)row * Bn + colc;
        float v = acc1[mt][nt][r] * sc + tc;
        if (do_relu) v = fmaxf(v, 0.0f);
        if constexpr (GATED) {
          float p = resid[base];
          float g = 1.0f / (1.0f + __expf(-(acc2[mt][nt][r] + gb)));
          v = g * p + (1.0f - g) * (v + p);
        } else if (resid) {
          v += resid[base];
        }
        C[base] = v;
      }
    }
  }
}

// ---------------- classifier stage 2: [M,128] @ [128,40] + b ----------------
__global__ __launch_bounds__(256)
void classifier2(const float* __restrict__ Tin, const float* __restrict__ W,
                 const float* __restrict__ bias, float* __restrict__ out, int M) {
  __shared__ float Ws[DIN * NCLS];
  __shared__ float bs[NCLS];
  __shared__ float Ts[64][DIN + 4];
  int tid = threadIdx.x;
  for (int i = tid; i < DIN * NCLS; i += 256) Ws[i] = W[i];
  if (tid < NCLS) bs[tid] = bias[tid];
  int row0 = blockIdx.x * 64;
  for (int idx = tid; idx < 64 * (DIN / 4); idx += 256) {
    int r = idx / (DIN / 4);
    int c4 = idx % (DIN / 4);
    float4 v = make_float4(0.f, 0.f, 0.f, 0.f);
    if (row0 + r < M) v = *reinterpret_cast<const float4*>(Tin + (long)(row0 + r) * DIN + c4 * 4);
    *reinterpret_cast<float4*>(&Ts[r][c4 * 4]) = v;
  }
  __syncthreads();
  int r = tid >> 2;
  int c0 = (tid & 3) * 10;
  float s[10];
#pragma unroll
  for (int c = 0; c < 10; c++) s[c] = bs[c0 + c];
  for (int k = 0; k < DIN; k++) {
    float a = Ts[r][k];
#pragma unroll
    for (int c = 0; c < 10; c++) s[c] = fmaf(a, Ws[k * NCLS + c0 + c], s[c]);
  }
  if (row0 + r < M) {
#pragma unroll
    for (int c = 0; c < 10; c++) out[(long)(row0 + r) * NCLS + c0 + c] = s[c];
  }
}

extern "C" void kernel_launch(void* const* d_in, const int* in_sizes, int n_in,
                              void* d_out, int out_size, void* d_ws, size_t ws_size,
                              hipStream_t stream) {
  const float* x      = (const float*)d_in[0];
  const int*   ei     = (const int*)d_in[1];
  const float* Wp     = (const float*)d_in[2];
  const float* bp     = (const float*)d_in[3];
  const float* W1l    = (const float*)d_in[4];
  const float* b1l    = (const float*)d_in[5];
  const float* W1r    = (const float*)d_in[6];
  const float* W2l    = (const float*)d_in[7];
  const float* b2l    = (const float*)d_in[8];
  const float* W2r    = (const float*)d_in[9];
  const float* bn1_g  = (const float*)d_in[10];
  const float* bn1_b  = (const float*)d_in[11];
  const float* bn1_m  = (const float*)d_in[12];
  const float* bn1_v  = (const float*)d_in[13];
  const float* bn2_g  = (const float*)d_in[14];
  const float* bn2_b  = (const float*)d_in[15];
  const float* bn2_m  = (const float*)d_in[16];
  const float* bn2_v  = (const float*)d_in[17];
  const float* gate_W = (const float*)d_in[18];
  const float* gate_b = (const float*)d_in[19];
  const float* Wc1    = (const float*)d_in[20];
  const float* bc1    = (const float*)d_in[21];
  const float* Wc2    = (const float*)d_in[22];
  const float* bc2    = (const float*)d_in[23];
  const int* srcp = ei;
  const int* dstp = ei + NEDGES;

  char* wsb = (char*)d_ws;
  size_t off = 0;
  auto alloc = [&](size_t bytes) -> void* {
    void* p = wsb + off;
    off += (bytes + 255) & ~(size_t)255;
    return p;
  };
  const size_t XFSZ = (size_t)MPAD * HID * 4;        // 51,249,152
  const size_t MPSZ = (size_t)NROWT * 8 * 12288;     // 76,873,728
  // big mode: 3 fp32 + mean-plane buffer (~240.6 MB total); else r8's 4 fp32 (~215 MB)
  const bool big = (ws_size >= 241000000ull);

  float* R[4] = {nullptr, nullptr, nullptr, nullptr};
  char* Mp = nullptr;
  if (big) {
    R[0] = (float*)alloc(XFSZ);
    R[1] = (float*)alloc(XFSZ);
    R[2] = (float*)alloc(XFSZ);
    Mp   = (char*)alloc(MPSZ);
  } else {
    R[0] = (float*)alloc(XFSZ);
    R[1] = (float*)alloc(XFSZ);
    R[2] = (float*)alloc(XFSZ);
    R[3] = (float*)alloc(XFSZ);
  }
  char* prep   = (char*)alloc(5898240);
  int* cnt     = (int*)alloc((size_t)NNODES * 4 * 2);
  int* fillc   = cnt + NNODES;
  int* row_ptr = (int*)alloc((size_t)(NNODES + 1) * 4);
  float* inv   = (float*)alloc((size_t)NNODES * 4);
  int* col     = (int*)alloc((size_t)NEDGES * 4);
  float* S1 = (float*)alloc(NBLK * HID * 4);
  float* T1 = (float*)alloc(NBLK * HID * 4);
  float* S2 = (float*)alloc(NBLK * HID * 4);
  float* T2 = (float*)alloc(NBLK * HID * 4);

  auto poff = [](int idx) -> unsigned {
    if (idx == 0) return 0;
    return 196608u + (unsigned)(idx - 1) * 393216u;
  };
  const char* prepWp  = prep + poff(0);
  auto prepW1l = [&](int i) { return prep + poff(1 + i); };
  auto prepW1r = [&](int i) { return prep + poff(4 + i); };
  auto prepW2l = [&](int i) { return prep + poff(7 + i); };
  auto prepW2r = [&](int i) { return prep + poff(10 + i); };
  auto prepGate = [&](int g) { return prep + poff(13 + g); };
  const char* prepWc1 = prep + poff(15);

  PrepDescs pd;
  {
    int c = 0, k = 0;
    auto add = [&](const float* s, int N, int chunks, unsigned doff) {
      pd.src[k] = s; pd.N[k] = N; c += chunks; pd.cum[k] = c; pd.dst_off[k] = doff; k++;
    };
    add(Wp, 256, 12288, poff(0));
    for (int i = 0; i < 3; i++) add(W1l + (size_t)i * 65536, 256, 24576, poff(1 + i));
    for (int i = 0; i < 3; i++) add(W1r + (size_t)i * 65536, 256, 24576, poff(4 + i));
    for (int i = 0; i < 3; i++) add(W2l + (size_t)i * 65536, 256, 24576, poff(7 + i));
    for (int i = 0; i < 3; i++) add(W2r + (size_t)i * 65536, 256, 24576, poff(10 + i));
    for (int g = 0; g < 2; g++) add(gate_W + (size_t)g * 65536, 256, 24576, poff(13 + g));
    add(Wc1, 128, 12288, poff(15));
  }

  hipMemsetAsync(cnt, 0, (size_t)NNODES * 4 * 2, stream);
  int eb = (NEDGES + 255) / 256;
  hist_kernel<<<eb, 256, 0, stream>>>(dstp, cnt, NEDGES);
  scan_kernel<<<1, 1024, 0, stream>>>(cnt, row_ptr, inv, NNODES);
  fill_kernel<<<eb, 256, 0, stream>>>(srcp, dstp, row_ptr, fillc, col, NEDGES);
  fold_kernel<<<3, 256, 0, stream>>>(b1l, bn1_g, bn1_b, bn1_m, bn1_v,
                                     b2l, bn2_g, bn2_b, bn2_m, bn2_v, S1, T1, S2, T2);
  prep_kernel<<<PREP_TOTAL / 256, 256, 0, stream>>>(pd, prep);

  const int gmw  = NROWT;       // 782 (Bn=128)
  const int g256 = NROWT * 2;   // 1564 (Bn=256)
  float* Tb = nullptr;

  // input projection: R[0] = x @ Wp + bp (fp32 A path, guarded at NNODES)
  gemm_mfma<false><<<g256, 256, 0, stream>>>(
      nullptr, x, prepWp, DIN, nullptr, nullptr, 0, nullptr, nullptr, nullptr,
      nullptr, bp, nullptr, R[0], 256, NNODES, 0);

  if (big) {
    int p = 0, h = 1, d = 2;
    for (int i = 0; i < NBLK; ++i) {
      agg_kernel<<<NNODES, 256, 0, stream>>>(R[p], nullptr, Mp, row_ptr, col, inv);
      gemm_mfma<false><<<g256, 256, 0, stream>>>(
          Mp, nullptr, prepW1l(i), HID, R[p], prepW1r(i), HID, nullptr, nullptr, nullptr,
          S1 + i * HID, T1 + i * HID, nullptr, R[h], 256, MPAD, 1);
      agg_kernel<<<NNODES, 256, 0, stream>>>(R[h], nullptr, Mp, row_ptr, col, inv);
      if (i == 0) {
        gemm_mfma<false><<<g256, 256, 0, stream>>>(
            Mp, nullptr, prepW2l(0), HID, R[h], prepW2r(0), HID, nullptr, nullptr, nullptr,
            S2, T2, R[p], R[d], 256, MPAD, 1);
      } else {
        gemm_mfma<true><<<g256, 256, 0, stream>>>(
            Mp, nullptr, prepW2l(i), HID, R[h], prepW2r(i), HID,
            R[p], prepGate(i - 1), gate_b + (size_t)(i - 1) * HID,
            S2 + i * HID, T2 + i * HID, R[p], R[d], 256, MPAD, 1);
      }
      int np = d, nh = p, nd = h;   // rotate: new P = old D
      p = np; h = nh; d = nd;
    }
    Tb = R[h];
    gemm_mfma<false><<<gmw, 256, 0, stream>>>(
        nullptr, R[p], prepWc1, HID, nullptr, nullptr, 0, nullptr, nullptr, nullptr,
        nullptr, bc1, nullptr, Tb, 128, MPAD, 1);
  } else {
    int ip = 0;
    for (int i = 0; i < NBLK; ++i) {
      int im = (ip + 1) & 3, ih = (ip + 2) & 3, id = (ip + 3) & 3;
      agg_kernel<<<NNODES, 256, 0, stream>>>(R[ip], R[im], nullptr, row_ptr, col, inv);
      gemm_mfma<false><<<g256, 256, 0, stream>>>(
          nullptr, R[im], prepW1l(i), HID, R[ip], prepW1r(i), HID, nullptr, nullptr, nullptr,
          S1 + i * HID, T1 + i * HID, nullptr, R[ih], 256, MPAD, 1);
      agg_kernel<<<NNODES, 256, 0, stream>>>(R[ih], R[im], nullptr, row_ptr, col, inv);
      if (i == 0) {
        gemm_mfma<false><<<g256, 256, 0, stream>>>(
            nullptr, R[im], prepW2l(0), HID, R[ih], prepW2r(0), HID, nullptr, nullptr, nullptr,
            S2, T2, R[ip], R[id], 256, MPAD, 1);
      } else {
        gemm_mfma<true><<<g256, 256, 0, stream>>>(
            nullptr, R[im], prepW2l(i), HID, R[ih], prepW2r(i), HID,
            R[ip], prepGate(i - 1), gate_b + (size_t)(i - 1) * HID,
            S2 + i * HID, T2 + i * HID, R[ip], R[id], 256, MPAD, 1);
      }
      ip = id;
    }
    Tb = R[(ip + 1) & 3];
    gemm_mfma<false><<<gmw, 256, 0, stream>>>(
        nullptr, R[ip], prepWc1, HID, nullptr, nullptr, 0, nullptr, nullptr, nullptr,
        nullptr, bc1, nullptr, Tb, 128, MPAD, 1);
  }
  classifier2<<<gmw, 256, 0, stream>>>(Tb, Wc2, bc2, (float*)d_out, NNODES);
}

// Round 11
// 1972.924 us; speedup vs baseline: 1.1064x; 1.1064x over previous
//
#include <hip/hip_runtime.h>
#include <hip/hip_bf16.h>
#include <cstdint>

#define NNODES 50000
#define MPAD   50048   // 782 * 64
#define NROWT  782     // MPAD/64
#define NEDGES 800000
#define DIN 128
#define HID 256
#define NCLS 40
#define NBLK 3
#define EPSV 1e-5f

typedef __bf16 bf16x8 __attribute__((ext_vector_type(8)));
typedef float  f32x4  __attribute__((ext_vector_type(4)));
typedef unsigned short us4v __attribute__((ext_vector_type(4)));
typedef unsigned short us8v __attribute__((ext_vector_type(8)));

// round-to-nearest-even fp32 -> bf16 bits
__device__ __forceinline__ unsigned short bf_rtn(float x) {
  unsigned u = __float_as_uint(x);
  return (unsigned short)((u + 0x7fffu + ((u >> 16) & 1u)) >> 16);
}
__device__ __forceinline__ float bf_f(unsigned short h) {
  return __uint_as_float((unsigned)h << 16);
}
// 3-plane split: x ~= h + m + l (each bf16)
__device__ __forceinline__ void split4(float4 a, us4v& h, us4v& m, us4v& l) {
  float v[4] = {a.x, a.y, a.z, a.w};
#pragma unroll
  for (int i = 0; i < 4; i++) {
    unsigned short hh = bf_rtn(v[i]);
    float r1 = v[i] - bf_f(hh);
    unsigned short mm = bf_rtn(r1);
    float r2 = r1 - bf_f(mm);
    h[i] = hh; m[i] = mm; l[i] = bf_rtn(r2);
  }
}

// Plane image of a 64x32 A-tile (12288 B): [plane 3][k8 0..3][row 0..63][16B].
// Global activation-plane buffer: [rowtile][ktile] x 12288 B, KT tiles per row.
__device__ __forceinline__ void plane_store(char* base, int KT, int r, int c, float v) {
  size_t o = ((size_t)((r >> 6) * KT + (c >> 5))) * 12288
           + (size_t)(((c >> 3) & 3) * 1024 + (r & 63) * 16 + (c & 7) * 2);
  unsigned short h = bf_rtn(v);
  float r1 = v - bf_f(h);
  unsigned short m = bf_rtn(r1);
  unsigned short l = bf_rtn(r1 - bf_f(m));
  *(unsigned short*)(base + o)        = h;
  *(unsigned short*)(base + o + 4096) = m;
  *(unsigned short*)(base + o + 8192) = l;
}

// async global->LDS, 16B per lane. gsrc is PER-LANE; ldst wave-uniform (HW adds lane*16).
__device__ __forceinline__ void glds16(const void* gsrc, void* ldst) {
  __builtin_amdgcn_global_load_lds((const __attribute__((address_space(1))) void*)gsrc,
                                   (__attribute__((address_space(3))) void*)ldst,
                                   16, 0, 0);
}

// ---------------- CSR build ----------------
__global__ void hist_kernel(const int* __restrict__ dst, int* __restrict__ cnt, int E) {
  int e = blockIdx.x * blockDim.x + threadIdx.x;
  if (e < E) atomicAdd(&cnt[dst[e]], 1);
}

__global__ void scan_kernel(const int* __restrict__ cnt, int* __restrict__ row_ptr,
                            float* __restrict__ inv_cnt, int N) {
  __shared__ int sums[1024];
  int t = threadIdx.x;
  int chunk = (N + 1023) >> 10;
  int beg = t * chunk;
  int end = beg + chunk; if (end > N) end = N;
  int s = 0;
  for (int i = beg; i < end; ++i) s += cnt[i];
  sums[t] = s;
  __syncthreads();
  for (int off = 1; off < 1024; off <<= 1) {
    int v = 0;
    if (t >= off) v = sums[t - off];
    __syncthreads();
    sums[t] += v;
    __syncthreads();
  }
  int run = (t == 0) ? 0 : sums[t - 1];
  for (int i = beg; i < end; ++i) {
    row_ptr[i] = run;
    int c = cnt[i];
    inv_cnt[i] = 1.0f / (float)(c > 0 ? c : 1);
    run += c;
  }
  if (t == 1023) row_ptr[N] = run;
}

__global__ void fill_kernel(const int* __restrict__ src, const int* __restrict__ dst,
                            const int* __restrict__ row_ptr, int* __restrict__ fillc,
                            int* __restrict__ col, int E) {
  int e = blockIdx.x * blockDim.x + threadIdx.x;
  if (e < E) {
    int d = dst[e];
    int pos = atomicAdd(&fillc[d], 1);
    col[row_ptr[d] + pos] = src[e];
  }
}

// ---------------- mean aggregation: 4 nodes/block, 1 wave/node, MLP x8 --------
// Lane l owns cols {l, l+64, l+128, l+192}; neighbor loop unrolled x2 -> 8
// independent 256B loads in flight per wave. Per-column add order identical to
// the sequential j-loop (c0's value added before c1's) -> bit-identical absmax.
__global__ __launch_bounds__(256)
void agg_kernel(const float* __restrict__ x, float* __restrict__ outf,
                char* __restrict__ outp,
                const int* __restrict__ row_ptr, const int* __restrict__ col,
                const float* __restrict__ inv_cnt) {
  const int wv   = threadIdx.x >> 6;
  const int lane = threadIdx.x & 63;
  const int n = blockIdx.x * 4 + wv;   // 12500*4 == 50000 exact
  int beg = row_ptr[n], end = row_ptr[n + 1];
  float s0 = 0.f, s1 = 0.f, s2 = 0.f, s3 = 0.f;
  int j = beg;
  for (; j + 1 < end; j += 2) {
    const float* xr0 = x + (size_t)col[j]     * HID + lane;
    const float* xr1 = x + (size_t)col[j + 1] * HID + lane;
    float a0 = xr0[0], a1 = xr0[64], a2 = xr0[128], a3 = xr0[192];
    float b0 = xr1[0], b1 = xr1[64], b2 = xr1[128], b3 = xr1[192];
    s0 += a0; s1 += a1; s2 += a2; s3 += a3;
    s0 += b0; s1 += b1; s2 += b2; s3 += b3;
  }
  if (j < end) {
    const float* xr0 = x + (size_t)col[j] * HID + lane;
    s0 += xr0[0]; s1 += xr0[64]; s2 += xr0[128]; s3 += xr0[192];
  }
  float ic = inv_cnt[n];
  if (outp) {
    plane_store(outp, 8, n, lane,       s0 * ic);
    plane_store(outp, 8, n, lane + 64,  s1 * ic);
    plane_store(outp, 8, n, lane + 128, s2 * ic);
    plane_store(outp, 8, n, lane + 192, s3 * ic);
  } else {
    float* o = outf + (size_t)n * HID + lane;
    o[0] = s0 * ic; o[64] = s1 * ic; o[128] = s2 * ic; o[192] = s3 * ic;
  }
}

// ---------------- fold BN params ----------------
__global__ void fold_kernel(const float* __restrict__ b1l, const float* __restrict__ g1,
                            const float* __restrict__ bb1, const float* __restrict__ m1,
                            const float* __restrict__ v1,
                            const float* __restrict__ b2l, const float* __restrict__ g2,
                            const float* __restrict__ bb2, const float* __restrict__ m2,
                            const float* __restrict__ v2,
                            float* __restrict__ S1, float* __restrict__ T1,
                            float* __restrict__ S2, float* __restrict__ T2) {
  int idx = blockIdx.x * 256 + threadIdx.x;  // 0..767
  float s1 = g1[idx] * rsqrtf(v1[idx] + EPSV);
  S1[idx] = s1;
  T1[idx] = (b1l[idx] - m1[idx]) * s1 + bb1[idx];
  float s2 = g2[idx] * rsqrtf(v2[idx] + EPSV);
  S2[idx] = s2;
  T2[idx] = (b2l[idx] - m2[idx]) * s2 + bb2[idx];
}

// ---------------- weight prep (layout unchanged from r6-r10) ----------------
#define PREP_TOTAL 368640
struct PrepDescs {
  const float* src[16];
  unsigned dst_off[16];
  int N[16];
  int cum[16];
};
__global__ __launch_bounds__(256)
void prep_kernel(PrepDescs pd, char* out) {
  int i = blockIdx.x * 256 + threadIdx.x;
  if (i >= PREP_TOTAL) return;
  int j = 0;
  while (i >= pd.cum[j]) j++;
  int li = i - (j ? pd.cum[j - 1] : 0);
  int c = li % 12;
  int t = li / 12;
  int N = pd.N[j];
  int n = t % N;
  int kt = t / N;
  const float* src = pd.src[j];
  char* base = out + pd.dst_off[j] + (size_t)kt * N * 192;
  int p, k8;
  size_t addr;
  if (c < 8) {
    int d = c ^ (n & 7);
    p = d >> 2; k8 = d & 3;
    addr = (size_t)n * 128 + (size_t)c * 16;
  } else {
    p = 2; k8 = c - 8;
    addr = (size_t)N * 128 + ((size_t)k8 * N + n) * 16;
  }
  us8v v;
#pragma unroll
  for (int xj = 0; xj < 8; xj++) {
    float w = src[(size_t)(kt * 32 + k8 * 8 + xj) * N + n];
    unsigned short h = bf_rtn(w);
    if (p == 0) { v[xj] = h; continue; }
    float r1 = w - bf_f(h);
    unsigned short m = bf_rtn(r1);
    v[xj] = (p == 1) ? m : bf_rtn(r1 - bf_f(m));
  }
  *reinterpret_cast<us8v*>(base + addr) = v;
}

// ---------------- fused 3-plane split-bf16 MFMA GEMM (unchanged from r10) -----
template<bool GATED>
__global__ __launch_bounds__(256)
void gemm_mfma(const char* __restrict__ A1p, const float* __restrict__ A1f,
               const char* __restrict__ B1, int K1,
               const float* __restrict__ A2f, const char* __restrict__ B2, int K2,
               const float* __restrict__ AGf, const char* __restrict__ BG,
               const float* __restrict__ Gb,
               const float* __restrict__ Sc, const float* __restrict__ Tc,
               const float* __restrict__ resid, float* __restrict__ C,
               int Bn, int Mguard, int do_relu) {
  __shared__ __align__(16) char A_lds[2][12288];
  __shared__ __align__(16) char B_lds[2][24576];
  const int tid  = threadIdx.x;
  const int wv   = tid >> 6;
  const int lane = tid & 63;
  const int l15  = lane & 15;
  const int quad = lane >> 4;
  const int NC   = Bn >> 7;
  const int n0   = (blockIdx.x % NC) * 128;
  const int m0   = (blockIdx.x / NC) * 64;
  const int rt   = m0 >> 6;
  const int wm   = wv >> 1;
  const int wn   = wv & 1;
  const int sr   = tid >> 3;
  const int c0   = (tid & 7) * 4;
  const int aoff = ((c0 >> 3) & 3) * 1024 + (c0 & 7) * 2;

  f32x4 acc1[2][4];
#pragma unroll
  for (int i = 0; i < 2; i++)
#pragma unroll
    for (int j = 0; j < 4; j++) acc1[i][j] = (f32x4){0.f, 0.f, 0.f, 0.f};
  f32x4 acc2[GATED ? 2 : 1][GATED ? 4 : 1];
  if constexpr (GATED) {
#pragma unroll
    for (int i = 0; i < 2; i++)
#pragma unroll
      for (int j = 0; j < 4; j++) acc2[i][j] = (f32x4){0.f, 0.f, 0.f, 0.f};
  }

  int buf = 0;

  auto issueApl = [&](const char* Ap, int KT, int kt, int b) {
    const char* src = Ap + ((size_t)(rt * KT + kt)) * 12288 + wv * 3072 + (size_t)lane * 16;
    char* dst = &A_lds[b][wv * 3072];
#pragma unroll
    for (int j = 0; j < 3; ++j)
      glds16(src + j * 1024, dst + j * 1024);
  };
  auto issueB = [&](const char* Bp, int kt, int b) {
    const char* tb = Bp + (size_t)kt * ((size_t)Bn * 192);
#pragma unroll
    for (int j = 0; j < 6; ++j) {
      int o = wv * 6144 + j * 1024;
      const char* src;
      if (o < 16384) {
        src = tb + (size_t)n0 * 128 + o;
      } else {
        int ol = o - 16384;
        int k8 = ol >> 11;
        int within = ol & 2047;
        src = tb + (size_t)Bn * 128 + (size_t)k8 * Bn * 16 + (size_t)n0 * 16 + within;
      }
      glds16(src + (size_t)lane * 16, &B_lds[b][o]);
    }
  };
  auto storeA = [&](float4 (&a)[2], int b) {
#pragma unroll
    for (int i = 0; i < 2; i++) {
      us4v h4, m4, l4;
      split4(a[i], h4, m4, l4);
      char* p0 = &A_lds[b][(size_t)(sr + i * 32) * 16 + aoff];
      *reinterpret_cast<us4v*>(p0)        = h4;
      *reinterpret_cast<us4v*>(p0 + 4096) = m4;
      *reinterpret_cast<us4v*>(p0 + 8192) = l4;
    }
  };

  auto phase = [&](const char* Apl, const float* Af, const char* Bp,
                   int K, f32x4 (&acc)[2][4]) {
    const int KT = K / 32;
    const bool pl = (Apl != nullptr);
    bool g[2];
    const float* ap[2];
    if (!pl) {
#pragma unroll
      for (int i = 0; i < 2; i++) {
        int row = m0 + sr + i * 32;
        g[i] = row < Mguard;
        ap[i] = Af + (size_t)row * K + c0;
      }
    }
    issueB(Bp, 0, buf);
    if (pl) {
      issueApl(Apl, KT, 0, buf);
    } else {
      float4 a[2];
#pragma unroll
      for (int i = 0; i < 2; i++)
        a[i] = g[i] ? *reinterpret_cast<const float4*>(ap[i]) : make_float4(0.f, 0.f, 0.f, 0.f);
      storeA(a, buf);
    }
    for (int kt = 0; kt < KT; ++kt) {
      __syncthreads();
      bf16x8 ah[2], am[2], al[2];
#pragma unroll
      for (int mt = 0; mt < 2; mt++) {
        const char* ra = &A_lds[buf][quad * 1024 + (size_t)(wm * 32 + mt * 16 + l15) * 16];
        ah[mt] = *reinterpret_cast<const bf16x8*>(ra);
        am[mt] = *reinterpret_cast<const bf16x8*>(ra + 4096);
        al[mt] = *reinterpret_cast<const bf16x8*>(ra + 8192);
      }
      bf16x8 bh[4], bm_[4], bl[4];
#pragma unroll
      for (int nt = 0; nt < 4; nt++) {
        int ln = wn * 64 + nt * 16 + l15;
        int sw = ln & 7;
        const char* rb = &B_lds[buf][(size_t)ln * 128];
        bh[nt]  = *reinterpret_cast<const bf16x8*>(rb + ((quad ^ sw) * 16));
        bm_[nt] = *reinterpret_cast<const bf16x8*>(rb + (((4 + quad) ^ sw) * 16));
        bl[nt]  = *reinterpret_cast<const bf16x8*>(
            &B_lds[buf][16384 + ((size_t)quad * 128 + ln) * 16]);
      }
      const bool pf = (kt + 1 < KT);
      float4 a[2];
      if (pf) {
        issueB(Bp, kt + 1, buf ^ 1);
        if (pl) {
          issueApl(Apl, KT, kt + 1, buf ^ 1);
        } else {
#pragma unroll
          for (int i = 0; i < 2; i++)
            a[i] = g[i] ? *reinterpret_cast<const float4*>(ap[i] + (kt + 1) * 32)
                        : make_float4(0.f, 0.f, 0.f, 0.f);
        }
      }
#pragma unroll
      for (int nt = 0; nt < 4; nt++) {
#pragma unroll
        for (int mt = 0; mt < 2; mt++) {
          acc[mt][nt] = __builtin_amdgcn_mfma_f32_16x16x32_bf16(ah[mt], bh[nt],  acc[mt][nt], 0, 0, 0);
          acc[mt][nt] = __builtin_amdgcn_mfma_f32_16x16x32_bf16(ah[mt], bm_[nt], acc[mt][nt], 0, 0, 0);
          acc[mt][nt] = __builtin_amdgcn_mfma_f32_16x16x32_bf16(am[mt], bh[nt],  acc[mt][nt], 0, 0, 0);
          acc[mt][nt] = __builtin_amdgcn_mfma_f32_16x16x32_bf16(am[mt], bm_[nt], acc[mt][nt], 0, 0, 0);
          acc[mt][nt] = __builtin_amdgcn_mfma_f32_16x16x32_bf16(ah[mt], bl[nt],  acc[mt][nt], 0, 0, 0);
          acc[mt][nt] = __builtin_amdgcn_mfma_f32_16x16x32_bf16(al[mt], bh[nt],  acc[mt][nt], 0, 0, 0);
        }
      }
      if (pf && !pl) storeA(a, buf ^ 1);
      buf ^= 1;
    }
  };

  phase(A1p, A1f, B1, K1, acc1);
  if (A2f) phase(nullptr, A2f, B2, K2, acc1);
  if constexpr (GATED) phase(nullptr, AGf, BG, HID, acc2);

#pragma unroll
  for (int nt = 0; nt < 4; nt++) {
    int colc = n0 + wn * 64 + nt * 16 + l15;
    float sc = Sc ? Sc[colc] : 1.0f;
    float tc = Tc[colc];
    float gb = 0.0f;
    if constexpr (GATED) gb = Gb[colc];
#pragma unroll
    for (int mt = 0; mt < 2; mt++) {
#pragma unroll
      for (int r = 0; r < 4; r++) {
        int row = m0 + wm * 32 + mt * 16 + quad * 4 + r;
        size_t base = (size_t)row * Bn + colc;
        float v = acc1[mt][nt][r] * sc + tc;
        if (do_relu) v = fmaxf(v, 0.0f);
        if constexpr (GATED) {
          float p = resid[base];
          float g = 1.0f / (1.0f + __expf(-(acc2[mt][nt][r] + gb)));
          v = g * p + (1.0f - g) * (v + p);
        } else if (resid) {
          v += resid[base];
        }
        C[base] = v;
      }
    }
  }
}

// ---------------- classifier stage 2: [M,128] @ [128,40] + b ----------------
__global__ __launch_bounds__(256)
void classifier2(const float* __restrict__ Tin, const float* __restrict__ W,
                 const float* __restrict__ bias, float* __restrict__ out, int M) {
  __shared__ float Ws[DIN * NCLS];
  __shared__ float bs[NCLS];
  __shared__ float Ts[64][DIN + 4];
  int tid = threadIdx.x;
  for (int i = tid; i < DIN * NCLS; i += 256) Ws[i] = W[i];
  if (tid < NCLS) bs[tid] = bias[tid];
  int row0 = blockIdx.x * 64;
  for (int idx = tid; idx < 64 * (DIN / 4); idx += 256) {
    int r = idx / (DIN / 4);
    int c4 = idx % (DIN / 4);
    float4 v = make_float4(0.f, 0.f, 0.f, 0.f);
    if (row0 + r < M) v = *reinterpret_cast<const float4*>(Tin + (long)(row0 + r) * DIN + c4 * 4);
    *reinterpret_cast<float4*>(&Ts[r][c4 * 4]) = v;
  }
  __syncthreads();
  int r = tid >> 2;
  int c0 = (tid & 3) * 10;
  float s[10];
#pragma unroll
  for (int c = 0; c < 10; c++) s[c] = bs[c0 + c];
  for (int k = 0; k < DIN; k++) {
    float a = Ts[r][k];
#pragma unroll
    for (int c = 0; c < 10; c++) s[c] = fmaf(a, Ws[k * NCLS + c0 + c], s[c]);
  }
  if (row0 + r < M) {
#pragma unroll
    for (int c = 0; c < 10; c++) out[(long)(row0 + r) * NCLS + c0 + c] = s[c];
  }
}

extern "C" void kernel_launch(void* const* d_in, const int* in_sizes, int n_in,
                              void* d_out, int out_size, void* d_ws, size_t ws_size,
                              hipStream_t stream) {
  const float* x      = (const float*)d_in[0];
  const int*   ei     = (const int*)d_in[1];
  const float* Wp     = (const float*)d_in[2];
  const float* bp     = (const float*)d_in[3];
  const float* W1l    = (const float*)d_in[4];
  const float* b1l    = (const float*)d_in[5];
  const float* W1r    = (const float*)d_in[6];
  const float* W2l    = (const float*)d_in[7];
  const float* b2l    = (const float*)d_in[8];
  const float* W2r    = (const float*)d_in[9];
  const float* bn1_g  = (const float*)d_in[10];
  const float* bn1_b  = (const float*)d_in[11];
  const float* bn1_m  = (const float*)d_in[12];
  const float* bn1_v  = (const float*)d_in[13];
  const float* bn2_g  = (const float*)d_in[14];
  const float* bn2_b  = (const float*)d_in[15];
  const float* bn2_m  = (const float*)d_in[16];
  const float* bn2_v  = (const float*)d_in[17];
  const float* gate_W = (const float*)d_in[18];
  const float* gate_b = (const float*)d_in[19];
  const float* Wc1    = (const float*)d_in[20];
  const float* bc1    = (const float*)d_in[21];
  const float* Wc2    = (const float*)d_in[22];
  const float* bc2    = (const float*)d_in[23];
  const int* srcp = ei;
  const int* dstp = ei + NEDGES;

  char* wsb = (char*)d_ws;
  size_t off = 0;
  auto alloc = [&](size_t bytes) -> void* {
    void* p = wsb + off;
    off += (bytes + 255) & ~(size_t)255;
    return p;
  };
  const size_t XFSZ = (size_t)MPAD * HID * 4;        // 51,249,152
  const size_t MPSZ = (size_t)NROWT * 8 * 12288;     // 76,873,728
  const bool big = (ws_size >= 241000000ull);

  float* R[4] = {nullptr, nullptr, nullptr, nullptr};
  char* Mp = nullptr;
  if (big) {
    R[0] = (float*)alloc(XFSZ);
    R[1] = (float*)alloc(XFSZ);
    R[2] = (float*)alloc(XFSZ);
    Mp   = (char*)alloc(MPSZ);
  } else {
    R[0] = (float*)alloc(XFSZ);
    R[1] = (float*)alloc(XFSZ);
    R[2] = (float*)alloc(XFSZ);
    R[3] = (float*)alloc(XFSZ);
  }
  char* prep   = (char*)alloc(5898240);
  int* cnt     = (int*)alloc((size_t)NNODES * 4 * 2);
  int* fillc   = cnt + NNODES;
  int* row_ptr = (int*)alloc((size_t)(NNODES + 1) * 4);
  float* inv   = (float*)alloc((size_t)NNODES * 4);
  int* col     = (int*)alloc((size_t)NEDGES * 4);
  float* S1 = (float*)alloc(NBLK * HID * 4);
  float* T1 = (float*)alloc(NBLK * HID * 4);
  float* S2 = (float*)alloc(NBLK * HID * 4);
  float* T2 = (float*)alloc(NBLK * HID * 4);

  auto poff = [](int idx) -> unsigned {
    if (idx == 0) return 0;
    return 196608u + (unsigned)(idx - 1) * 393216u;
  };
  const char* prepWp  = prep + poff(0);
  auto prepW1l = [&](int i) { return prep + poff(1 + i); };
  auto prepW1r = [&](int i) { return prep + poff(4 + i); };
  auto prepW2l = [&](int i) { return prep + poff(7 + i); };
  auto prepW2r = [&](int i) { return prep + poff(10 + i); };
  auto prepGate = [&](int g) { return prep + poff(13 + g); };
  const char* prepWc1 = prep + poff(15);

  PrepDescs pd;
  {
    int c = 0, k = 0;
    auto add = [&](const float* s, int N, int chunks, unsigned doff) {
      pd.src[k] = s; pd.N[k] = N; c += chunks; pd.cum[k] = c; pd.dst_off[k] = doff; k++;
    };
    add(Wp, 256, 12288, poff(0));
    for (int i = 0; i < 3; i++) add(W1l + (size_t)i * 65536, 256, 24576, poff(1 + i));
    for (int i = 0; i < 3; i++) add(W1r + (size_t)i * 65536, 256, 24576, poff(4 + i));
    for (int i = 0; i < 3; i++) add(W2l + (size_t)i * 65536, 256, 24576, poff(7 + i));
    for (int i = 0; i < 3; i++) add(W2r + (size_t)i * 65536, 256, 24576, poff(10 + i));
    for (int g = 0; g < 2; g++) add(gate_W + (size_t)g * 65536, 256, 24576, poff(13 + g));
    add(Wc1, 128, 12288, poff(15));
  }

  hipMemsetAsync(cnt, 0, (size_t)NNODES * 4 * 2, stream);
  int eb = (NEDGES + 255) / 256;
  hist_kernel<<<eb, 256, 0, stream>>>(dstp, cnt, NEDGES);
  scan_kernel<<<1, 1024, 0, stream>>>(cnt, row_ptr, inv, NNODES);
  fill_kernel<<<eb, 256, 0, stream>>>(srcp, dstp, row_ptr, fillc, col, NEDGES);
  fold_kernel<<<3, 256, 0, stream>>>(b1l, bn1_g, bn1_b, bn1_m, bn1_v,
                                     b2l, bn2_g, bn2_b, bn2_m, bn2_v, S1, T1, S2, T2);
  prep_kernel<<<PREP_TOTAL / 256, 256, 0, stream>>>(pd, prep);

  const int gmw  = NROWT;       // 782 (Bn=128)
  const int g256 = NROWT * 2;   // 1564 (Bn=256)
  const int gagg = NNODES / 4;  // 12500
  float* Tb = nullptr;

  gemm_mfma<false><<<g256, 256, 0, stream>>>(
      nullptr, x, prepWp, DIN, nullptr, nullptr, 0, nullptr, nullptr, nullptr,
      nullptr, bp, nullptr, R[0], 256, NNODES, 0);

  if (big) {
    int p = 0, h = 1, d = 2;
    for (int i = 0; i < NBLK; ++i) {
      agg_kernel<<<gagg, 256, 0, stream>>>(R[p], nullptr, Mp, row_ptr, col, inv);
      gemm_mfma<false><<<g256, 256, 0, stream>>>(
          Mp, nullptr, prepW1l(i), HID, R[p], prepW1r(i), HID, nullptr, nullptr, nullptr,
          S1 + i * HID, T1 + i * HID, nullptr, R[h], 256, MPAD, 1);
      agg_kernel<<<gagg, 256, 0, stream>>>(R[h], nullptr, Mp, row_ptr, col, inv);
      if (i == 0) {
        gemm_mfma<false><<<g256, 256, 0, stream>>>(
            Mp, nullptr, prepW2l(0), HID, R[h], prepW2r(0), HID, nullptr, nullptr, nullptr,
            S2, T2, R[p], R[d], 256, MPAD, 1);
      } else {
        gemm_mfma<true><<<g256, 256, 0, stream>>>(
            Mp, nullptr, prepW2l(i), HID, R[h], prepW2r(i), HID,
            R[p], prepGate(i - 1), gate_b + (size_t)(i - 1) * HID,
            S2 + i * HID, T2 + i * HID, R[p], R[d], 256, MPAD, 1);
      }
      int np = d, nh = p, nd = h;
      p = np; h = nh; d = nd;
    }
    Tb = R[h];
    gemm_mfma<false><<<gmw, 256, 0, stream>>>(
        nullptr, R[p], prepWc1, HID, nullptr, nullptr, 0, nullptr, nullptr, nullptr,
        nullptr, bc1, nullptr, Tb, 128, MPAD, 1);
  } else {
    int ip = 0;
    for (int i = 0; i < NBLK; ++i) {
      int im = (ip + 1) & 3, ih = (ip + 2) & 3, id = (ip + 3) & 3;
      agg_kernel<<<gagg, 256, 0, stream>>>(R[ip], R[im], nullptr, row_ptr, col, inv);
      gemm_mfma<false><<<g256, 256, 0, stream>>>(
          nullptr, R[im], prepW1l(i), HID, R[ip], prepW1r(i), HID, nullptr, nullptr, nullptr,
          S1 + i * HID, T1 + i * HID, nullptr, R[ih], 256, MPAD, 1);
      agg_kernel<<<gagg, 256, 0, stream>>>(R[ih], R[im], nullptr, row_ptr, col, inv);
      if (i == 0) {
        gemm_mfma<false><<<g256, 256, 0, stream>>>(
            nullptr, R[im], prepW2l(0), HID, R[ih], prepW2r(0), HID, nullptr, nullptr, nullptr,
            S2, T2, R[ip], R[id], 256, MPAD, 1);
      } else {
        gemm_mfma<true><<<g256, 256, 0, stream>>>(
            nullptr, R[im], prepW2l(i), HID, R[ih], prepW2r(i), HID,
            R[ip], prepGate(i - 1), gate_b + (size_t)(i - 1) * HID,
            S2 + i * HID, T2 + i * HID, R[ip], R[id], 256, MPAD, 1);
      }
      ip = id;
    }
    Tb = R[(ip + 1) & 3];
    gemm_mfma<false><<<gmw, 256, 0, stream>>>(
        nullptr, R[ip], prepWc1, HID, nullptr, nullptr, 0, nullptr, nullptr, nullptr,
        nullptr, bc1, nullptr, Tb, 128, MPAD, 1);
  }
  classifier2<<<gmw, 256, 0, stream>>>(Tb, Wc2, bc2, (float*)d_out, NNODES);
}